// Round 1
// baseline (26.213 us; speedup 1.0000x reference)
//
#include <hip/hip_runtime.h>

#define GROUPS 4
#define POINTS 120

// out[i] = data[i] * (1 + dy_g) + dx_g, g = i % 4.
// dy_g = velo0_g*0.01*sin(theta0_g), dx_g = velo0_g*0.01*cos(theta0_g),
// where theta0_g = params[0][g][0], velo0_g = params[1][g][0]
// (the reference's _by_tanh degenerates to frame[0] because hi == 0).
__global__ __launch_bounds__(256) void foil_affine_kernel(
    const float* __restrict__ data,
    const float* __restrict__ params,
    float* __restrict__ out,
    int n4)
{
    __shared__ float s_a[GROUPS];  // 1 + dy_g
    __shared__ float s_b[GROUPS];  // dx_g

    if (threadIdx.x < GROUPS) {
        int g = (int)threadIdx.x;
        float th0 = params[g * POINTS];                  // params[0][g][0]
        float v0  = params[GROUPS * POINTS + g * POINTS]; // params[1][g][0]
        float ds  = v0 * 0.01f;
        s_b[g] = ds * cosf(th0);
        s_a[g] = 1.0f + ds * sinf(th0);
    }
    __syncthreads();

    const float4 a = make_float4(s_a[0], s_a[1], s_a[2], s_a[3]);
    const float4 b = make_float4(s_b[0], s_b[1], s_b[2], s_b[3]);

    const float4* __restrict__ in4  = (const float4*)data;
    float4*       __restrict__ out4 = (float4*)out;

    int stride = gridDim.x * blockDim.x;
    for (int i = blockIdx.x * blockDim.x + threadIdx.x; i < n4; i += stride) {
        float4 v = in4[i];
        float4 o;
        o.x = fmaf(v.x, a.x, b.x);
        o.y = fmaf(v.y, a.y, b.y);
        o.z = fmaf(v.z, a.z, b.z);
        o.w = fmaf(v.w, a.w, b.w);
        out4[i] = o;
    }
}

extern "C" void kernel_launch(void* const* d_in, const int* in_sizes, int n_in,
                              void* d_out, int out_size, void* d_ws, size_t ws_size,
                              hipStream_t stream) {
    const float* data   = (const float*)d_in[0];
    const float* params = (const float*)d_in[1];
    float* out = (float*)d_out;

    int n  = in_sizes[0];      // 4096*4096, divisible by 4
    int n4 = n / 4;

    const int threads = 256;
    int blocks = 2048;         // 256 CUs * 8 blocks/CU; grid-stride covers the rest
    int needed = (n4 + threads - 1) / threads;
    if (blocks > needed) blocks = needed;

    foil_affine_kernel<<<blocks, threads, 0, stream>>>(data, params, out, n4);
}